// Round 4
// baseline (270.856 us; speedup 1.0000x reference)
//
#include <hip/hip_runtime.h>
#include <hip/hip_bf16.h>
#include <stdint.h>

// ViewLoRALinear: out[25088,1024] = x@W^T + b + (x@A_v)@B_v, fp32 in/out.
// Prep kernel casts x,W to bf16 (RNE) into d_ws and computes h = x@A_v in a
// single fused pass over x.
// GEMM (round 4): 128x128 tile, BK=32 DOUBLE-BUFFERED LDS (2x8KB per matrix
// = 32 KB total, SAME footprint as round-3's single BK=64 buffer -> keeps
// the 4-blocks/CU residency that round 3 proved critical: 60 VGPR + 64 AGPR
// = 124/wave). Per iteration: issue STAGE(kt+1 -> buf^1) FIRST, then
// ds_read+MFMA of buf, then one __syncthreads() (its implicit vmcnt(0)
// drain now lands AFTER a full compute phase of overlap instead of exposing
// the global->LDS latency on the critical path). This is the catalog's
// "minimum 2-phase" schedule (92% of full 8-phase, measured), expressed with
// plain __syncthreads so the compiler's memory semantics stay correct.
// Swizzle at BK=32 (4 chunks of 8 elems per row): source chunk c^((r>>1)&3),
// fragment read chunk quad^((l16>>1)&3) -> 2 lanes per bank group (free).
#define M_TOT 25088
#define N_TOT 1024
#define K_TOT 1024
#define NVIEW 11
#define ROWS_PER_VIEW 1568   // 8 frames * 196 tokens per view_idx entry

#define BM 128
#define BN 128

typedef unsigned short u16;
typedef __bf16 bf16x8 __attribute__((ext_vector_type(8)));
typedef float f32x4 __attribute__((ext_vector_type(4)));
typedef unsigned short u16x4 __attribute__((ext_vector_type(4)));

#define AS1 __attribute__((address_space(1)))
#define AS3 __attribute__((address_space(3)))

// ws layout (fast path): [x_bf16: 25088*1024 u16][W_bf16: 1024*1024 u16][h: 25088*4 f32]
#define XB_ELEMS ((size_t)M_TOT * K_TOT)
#define WB_ELEMS ((size_t)N_TOT * K_TOT)
#define WB_OFF_B (XB_ELEMS * 2)
#define H_OFF_B  (WB_OFF_B + WB_ELEMS * 2)
#define WS_NEEDED (H_OFF_B + (size_t)M_TOT * 4 * 4)

__device__ __forceinline__ u16 f2bf(float f) {
    union { float f; unsigned int i; } c; c.f = f;
    unsigned int i = c.i;
    return (u16)((i + 0x7FFFu + ((i >> 16) & 1u)) >> 16);  // RNE (finite inputs)
}

// ---------------------------------------------------------------------------
// Kernel 1: prep. Blocks 0..6271: one x-row per wave -> bf16 cast + h[row]
// in a SINGLE fused pass. Blocks 6272..6527: one W-row per wave -> bf16 cast.
// ---------------------------------------------------------------------------
__global__ __launch_bounds__(256) void prep_kernel(
    const float* __restrict__ x, const float* __restrict__ W,
    const int* __restrict__ view_idx, const float* __restrict__ lora_A,
    u16* __restrict__ xb, u16* __restrict__ wb, float* __restrict__ h) {
    const int wave = threadIdx.x >> 6;
    const int lane = threadIdx.x & 63;
    const int blk  = blockIdx.x;

    if (blk >= M_TOT / 4) {  // W cast
        const int row = (blk - M_TOT / 4) * 4 + wave;
        const float* src = W + (size_t)row * K_TOT;
        u16* dst = wb + (size_t)row * K_TOT;
#pragma unroll
        for (int it = 0; it < 4; ++it) {
            const int k = it * 256 + lane * 4;
            float4 v = *(const float4*)(src + k);
            u16x4 o = { f2bf(v.x), f2bf(v.y), f2bf(v.z), f2bf(v.w) };
            *(u16x4*)(dst + k) = o;
        }
        return;
    }

    const int row = blk * 4 + wave;
    int v = view_idx[row / ROWS_PER_VIEW];
    v = v < 0 ? 0 : (v > NVIEW - 1 ? NVIEW - 1 : v);
    const float* A  = lora_A + (size_t)v * (K_TOT * 4);  // [K][4] row-major
    const float* xr = x + (size_t)row * K_TOT;
    u16* dst = xb + (size_t)row * K_TOT;

    float a0 = 0.f, a1 = 0.f, a2 = 0.f, a3 = 0.f;
#pragma unroll
    for (int it = 0; it < 4; ++it) {
        const int k = it * 256 + lane * 4;
        float4 xv = *(const float4*)(xr + k);
        u16x4 o = { f2bf(xv.x), f2bf(xv.y), f2bf(xv.z), f2bf(xv.w) };
        *(u16x4*)(dst + k) = o;
        float4 av0 = *(const float4*)(A + (size_t)(k + 0) * 4);
        float4 av1 = *(const float4*)(A + (size_t)(k + 1) * 4);
        float4 av2 = *(const float4*)(A + (size_t)(k + 2) * 4);
        float4 av3 = *(const float4*)(A + (size_t)(k + 3) * 4);
        a0 += xv.x * av0.x + xv.y * av1.x + xv.z * av2.x + xv.w * av3.x;
        a1 += xv.x * av0.y + xv.y * av1.y + xv.z * av2.y + xv.w * av3.y;
        a2 += xv.x * av0.z + xv.y * av1.z + xv.z * av2.z + xv.w * av3.z;
        a3 += xv.x * av0.w + xv.y * av1.w + xv.z * av2.w + xv.w * av3.w;
    }
#pragma unroll
    for (int off = 32; off > 0; off >>= 1) {
        a0 += __shfl_xor(a0, off, 64);
        a1 += __shfl_xor(a1, off, 64);
        a2 += __shfl_xor(a2, off, 64);
        a3 += __shfl_xor(a3, off, 64);
    }
    if (lane == 0)
        *(float4*)(h + (size_t)row * 4) = make_float4(a0, a1, a2, a3);
}

// Fallback h (ws too small): fp32 x, one wave/row.
__global__ __launch_bounds__(256) void h_only_kernel(
    const float* __restrict__ x, const int* __restrict__ view_idx,
    const float* __restrict__ lora_A, float* __restrict__ h) {
    const int row  = blockIdx.x * 4 + (threadIdx.x >> 6);
    const int lane = threadIdx.x & 63;
    int v = view_idx[row / ROWS_PER_VIEW];
    v = v < 0 ? 0 : (v > NVIEW - 1 ? NVIEW - 1 : v);
    const float* A  = lora_A + (size_t)v * (K_TOT * 4);
    const float* xr = x + (size_t)row * K_TOT;
    float a0 = 0.f, a1 = 0.f, a2 = 0.f, a3 = 0.f;
#pragma unroll
    for (int it = 0; it < 4; ++it) {
        const int k = it * 256 + lane * 4;
        float4 xv = *(const float4*)(xr + k);
        float4 av0 = *(const float4*)(A + (size_t)(k + 0) * 4);
        float4 av1 = *(const float4*)(A + (size_t)(k + 1) * 4);
        float4 av2 = *(const float4*)(A + (size_t)(k + 2) * 4);
        float4 av3 = *(const float4*)(A + (size_t)(k + 3) * 4);
        a0 += xv.x * av0.x + xv.y * av1.x + xv.z * av2.x + xv.w * av3.x;
        a1 += xv.x * av0.y + xv.y * av1.y + xv.z * av2.y + xv.w * av3.y;
        a2 += xv.x * av0.z + xv.y * av1.z + xv.z * av2.z + xv.w * av3.z;
        a3 += xv.x * av0.w + xv.y * av1.w + xv.z * av2.w + xv.w * av3.w;
    }
#pragma unroll
    for (int off = 32; off > 0; off >>= 1) {
        a0 += __shfl_xor(a0, off, 64);
        a1 += __shfl_xor(a1, off, 64);
        a2 += __shfl_xor(a2, off, 64);
        a3 += __shfl_xor(a3, off, 64);
    }
    if (lane == 0)
        *(float4*)(h + (size_t)row * 4) = make_float4(a0, a1, a2, a3);
}

// ---------------------------------------------------------------------------
// Kernel 2 (fast path): GEMM C = X*W^T + bias + h*B_v, fp32 out.
// BK=32, double-buffered LDS, stage-before-compute, one barrier/iter.
// ---------------------------------------------------------------------------
__device__ __forceinline__ void stage32(const u16* __restrict__ gA,
                                        const u16* __restrict__ gB,
                                        u16* lA, u16* lB, int kofs, int tid) {
    // 128 rows x 32 cols bf16 = 8 KB per matrix; 256 thr x 16 B x 2 sweeps.
    // LDS dst linear (tid*16B); XOR swizzle on the SOURCE chunk: row r keeps
    // its 64B window [kofs, kofs+32) but chunk cc (16B) comes from cc^((r>>1)&3).
#pragma unroll
    for (int i = 0; i < 2; ++i) {
        const int e  = i * 2048 + tid * 8;       // LDS elem offset (contiguous)
        const int r  = e >> 5;                   // tile row (32 elems/row)
        const int cc = tid & 3;                  // dst chunk within row
        const int c  = ((cc ^ ((r >> 1) & 3)) << 3);  // swizzled source chunk
        __builtin_amdgcn_global_load_lds(
            (const AS1 void*)(gA + (size_t)r * K_TOT + kofs + c),
            (AS3 void*)(lA + e), 16, 0, 0);
        __builtin_amdgcn_global_load_lds(
            (const AS1 void*)(gB + (size_t)r * K_TOT + kofs + c),
            (AS3 void*)(lB + e), 16, 0, 0);
    }
}

__global__ __launch_bounds__(256, 3) void gemm_bf16_kernel(
    const u16* __restrict__ xb, const u16* __restrict__ wb,
    const float* __restrict__ bias, const int* __restrict__ view_idx,
    const float* __restrict__ lora_B, const float* __restrict__ h,
    float* __restrict__ out) {
    __shared__ u16 As[2][BM * 32];   // 2 x 8 KB
    __shared__ u16 Bs[2][BN * 32];   // 2 x 8 KB  (32 KB total)

    const int tid = threadIdx.x;
    // XCD swizzle: xcd = id%8; XCD x sweeps all 8 bx of by = c*8 + x.
    const int id = blockIdx.x;
    int bx, by;
    if (id < 1536) { const int c = id >> 6, w = id & 63; by = c * 8 + (w & 7); bx = w >> 3; }
    else           { const int r = id - 1536; by = 192 + (r & 3); bx = r >> 2; }

    const int lane = tid & 63;
    const int wave = tid >> 6;
    const int wm   = (wave >> 1) * 64;
    const int wn   = (wave & 1) * 64;
    const int l16  = lane & 15;
    const int quad = lane >> 4;
    const int sw2  = (l16 >> 1) & 3;            // fragment-read XOR key (BK=32)
    const int csw  = ((quad ^ sw2) << 3);       // swizzled chunk byte... elem offset

    const u16* gA = xb + (size_t)(by * BM) * K_TOT;
    const u16* gB = wb + (size_t)(bx * BN) * K_TOT;

    f32x4 acc[4][4] = {};

    // Prologue: tile 0 into buffer 0.
    stage32(gA, gB, &As[0][0], &Bs[0][0], 0, tid);
    __syncthreads();   // vmcnt(0) drain + barrier: tile 0 visible

    #pragma unroll 2
    for (int kt = 0; kt < K_TOT / 32; ++kt) {
        const int buf  = kt & 1;
        const int nbuf = buf ^ 1;

        // Issue next tile's staging FIRST (targets the other buffer) so its
        // global->LDS latency overlaps this tile's ds_read + MFMA.
        if (kt + 1 < K_TOT / 32)
            stage32(gA, gB, &As[nbuf][0], &Bs[nbuf][0], (kt + 1) * 32, tid);

        bf16x8 a_frag[4], b_frag[4];
#pragma unroll
        for (int mi = 0; mi < 4; ++mi)
            a_frag[mi] = *(const bf16x8*)(const void*)(
                &As[buf][0] + (wm + mi * 16 + l16) * 32 + csw);
#pragma unroll
        for (int ni = 0; ni < 4; ++ni)
            b_frag[ni] = *(const bf16x8*)(const void*)(
                &Bs[buf][0] + (wn + ni * 16 + l16) * 32 + csw);
#pragma unroll
        for (int mi = 0; mi < 4; ++mi)
#pragma unroll
            for (int ni = 0; ni < 4; ++ni)
                acc[mi][ni] = __builtin_amdgcn_mfma_f32_16x16x32_bf16(
                    a_frag[mi], b_frag[ni], acc[mi][ni], 0, 0, 0);

        // One barrier per iter. Implicit vmcnt(0) waits for the kt+1 stage
        // issued ABOVE -- after a full compute phase of overlap.
        __syncthreads();
    }

    // Epilogue. C/D layout (m89): col = lane&15, row = quad*4 + reg.
    const int rowBase = by * BM + wm;
    const int colBase = bx * BN + wn;
    float biasv[4];
#pragma unroll
    for (int ni = 0; ni < 4; ++ni) biasv[ni] = bias[colBase + ni * 16 + l16];

    const int ve0 = (by * BM) / ROWS_PER_VIEW;
    const int ve1 = (by * BM + BM - 1) / ROWS_PER_VIEW;
    if (ve0 == ve1) {
        int v = view_idx[ve0];
        v = v < 0 ? 0 : (v > NVIEW - 1 ? NVIEW - 1 : v);
        const float* Bv = lora_B + (size_t)v * (4 * N_TOT);
        float Bvv[4][4];
#pragma unroll
        for (int r = 0; r < 4; ++r)
#pragma unroll
            for (int ni = 0; ni < 4; ++ni)
                Bvv[r][ni] = Bv[r * N_TOT + colBase + ni * 16 + l16];
#pragma unroll
        for (int mi = 0; mi < 4; ++mi) {
#pragma unroll
            for (int reg = 0; reg < 4; ++reg) {
                const int grow = rowBase + mi * 16 + quad * 4 + reg;
                const float4 hv = *(const float4*)(h + (size_t)grow * 4);
                float* orow = out + (size_t)grow * N_TOT;
#pragma unroll
                for (int ni = 0; ni < 4; ++ni) {
                    float lora = hv.x * Bvv[0][ni] + hv.y * Bvv[1][ni]
                               + hv.z * Bvv[2][ni] + hv.w * Bvv[3][ni];
                    orow[colBase + ni * 16 + l16] = acc[mi][ni][reg] + biasv[ni] + lora;
                }
            }
        }
    } else {
#pragma unroll
        for (int mi = 0; mi < 4; ++mi) {
#pragma unroll
            for (int reg = 0; reg < 4; ++reg) {
                const int grow = rowBase + mi * 16 + quad * 4 + reg;
                int v = view_idx[grow / ROWS_PER_VIEW];
                v = v < 0 ? 0 : (v > NVIEW - 1 ? NVIEW - 1 : v);
                const float4 hv = *(const float4*)(h + (size_t)grow * 4);
                const float* Bv = lora_B + (size_t)v * (4 * N_TOT);
                float* orow = out + (size_t)grow * N_TOT;
#pragma unroll
                for (int ni = 0; ni < 4; ++ni) {
                    const int gcol = colBase + ni * 16 + l16;
                    float lora = hv.x * Bv[gcol]
                               + hv.y * Bv[N_TOT + gcol]
                               + hv.z * Bv[2 * N_TOT + gcol]
                               + hv.w * Bv[3 * N_TOT + gcol];
                    orow[gcol] = acc[mi][ni][reg] + biasv[ni] + lora;
                }
            }
        }
    }
}

// ---------------------------------------------------------------------------
// Fallback GEMM (ws too small): 128x128, BK=64, in-kernel bf16 cast
// (round-3 structure, reg-staged swizzled LDS writes).
// ---------------------------------------------------------------------------
__global__ __launch_bounds__(256, 3) void gemm_conv_kernel(
    const float* __restrict__ xp, const float* __restrict__ Wp,
    const float* __restrict__ bias, const int* __restrict__ view_idx,
    const float* __restrict__ lora_B, const float* __restrict__ h,
    float* __restrict__ out) {
    __shared__ u16 As[BM * 64];
    __shared__ u16 Bs[BN * 64];

    const int tid = threadIdx.x;
    const int id = blockIdx.x;
    int bx, by;
    if (id < 1536) { const int c = id >> 6, w = id & 63; by = c * 8 + (w & 7); bx = w >> 3; }
    else           { const int r = id - 1536; by = 192 + (r & 3); bx = r >> 2; }

    const int lane = tid & 63;
    const int wave = tid >> 6;
    const int wm   = (wave >> 1) * 64;
    const int wn   = (wave & 1) * 64;
    const int l16  = lane & 15;
    const int quad = lane >> 4;
    const int sw   = l16 & 7;

    const size_t a_base = (size_t)(by * BM) * K_TOT;
    const size_t b_base = (size_t)(bx * BN) * K_TOT;

    f32x4 acc[4][4] = {};

    for (int kt = 0; kt < K_TOT / 64; ++kt) {
        const int kofs = kt * 64;
#pragma unroll
        for (int i = 0; i < 8; ++i) {
            const int e = i * 1024 + tid * 4;
            const int r = e >> 6, o = e & 63;
            const int d = r * 64 + (((o >> 3) ^ (r & 7)) << 3) + (o & 7);
            float4 av = *(const float4*)(xp + a_base + (size_t)r * K_TOT + kofs + o);
            float4 bv = *(const float4*)(Wp + b_base + (size_t)r * K_TOT + kofs + o);
            u16x4 ao = { f2bf(av.x), f2bf(av.y), f2bf(av.z), f2bf(av.w) };
            u16x4 bo = { f2bf(bv.x), f2bf(bv.y), f2bf(bv.z), f2bf(bv.w) };
            *(u16x4*)(As + d) = ao;
            *(u16x4*)(Bs + d) = bo;
        }
        __syncthreads();
#pragma unroll
        for (int kk = 0; kk < 2; ++kk) {
            const int csw = (((kk * 4 + quad) ^ sw) << 3);
            bf16x8 a_frag[4], b_frag[4];
#pragma unroll
            for (int mi = 0; mi < 4; ++mi)
                a_frag[mi] = *(const bf16x8*)(const void*)(As + (wm + mi * 16 + l16) * 64 + csw);
#pragma unroll
            for (int ni = 0; ni < 4; ++ni)
                b_frag[ni] = *(const bf16x8*)(const void*)(Bs + (wn + ni * 16 + l16) * 64 + csw);
#pragma unroll
            for (int mi = 0; mi < 4; ++mi)
#pragma unroll
                for (int ni = 0; ni < 4; ++ni)
                    acc[mi][ni] = __builtin_amdgcn_mfma_f32_16x16x32_bf16(
                        a_frag[mi], b_frag[ni], acc[mi][ni], 0, 0, 0);
        }
        __syncthreads();
    }

    const int rowBase = by * BM + wm;
    const int colBase = bx * BN + wn;
    float biasv[4];
#pragma unroll
    for (int ni = 0; ni < 4; ++ni) biasv[ni] = bias[colBase + ni * 16 + l16];
#pragma unroll
    for (int mi = 0; mi < 4; ++mi) {
#pragma unroll
        for (int reg = 0; reg < 4; ++reg) {
            const int grow = rowBase + mi * 16 + quad * 4 + reg;
            int v = view_idx[grow / ROWS_PER_VIEW];
            v = v < 0 ? 0 : (v > NVIEW - 1 ? NVIEW - 1 : v);
            const float4 hv = *(const float4*)(h + (size_t)grow * 4);
            const float* Bv = lora_B + (size_t)v * (4 * N_TOT);
            float* orow = out + (size_t)grow * N_TOT;
#pragma unroll
            for (int ni = 0; ni < 4; ++ni) {
                const int gcol = colBase + ni * 16 + l16;
                float lora = hv.x * Bv[gcol]
                           + hv.y * Bv[N_TOT + gcol]
                           + hv.z * Bv[2 * N_TOT + gcol]
                           + hv.w * Bv[3 * N_TOT + gcol];
                orow[gcol] = acc[mi][ni][reg] + biasv[ni] + lora;
            }
        }
    }
}

extern "C" void kernel_launch(void* const* d_in, const int* in_sizes, int n_in,
                              void* d_out, int out_size, void* d_ws, size_t ws_size,
                              hipStream_t stream) {
    const float* x        = (const float*)d_in[0];
    const int*   view_idx = (const int*)d_in[1];
    const float* W        = (const float*)d_in[2];
    const float* b        = (const float*)d_in[3];
    const float* lora_A   = (const float*)d_in[4];
    const float* lora_B   = (const float*)d_in[5];
    float* out = (float*)d_out;

    const dim3 ggrid((M_TOT / BM) * (N_TOT / BN));  // 1568, swizzled in-kernel
    if (ws_size >= WS_NEEDED) {
        u16*   xb = (u16*)d_ws;
        u16*   wb = (u16*)((char*)d_ws + WB_OFF_B);
        float* h  = (float*)((char*)d_ws + H_OFF_B);
        hipLaunchKernelGGL(prep_kernel, dim3(M_TOT / 4 + N_TOT / 4), dim3(256), 0, stream,
                           x, W, view_idx, lora_A, xb, wb, h);
        hipLaunchKernelGGL(gemm_bf16_kernel, ggrid, dim3(256), 0, stream,
                           xb, wb, b, view_idx, lora_B, h, out);
    } else {
        float* h = (float*)d_ws;  // 401,408 B
        hipLaunchKernelGGL(h_only_kernel, dim3(M_TOT / 4), dim3(256), 0, stream,
                           x, view_idx, lora_A, h);
        hipLaunchKernelGGL(gemm_conv_kernel, ggrid, dim3(256), 0, stream,
                           x, W, b, view_idx, lora_B, h, out);
    }
}

// Round 5
// 257.768 us; speedup vs baseline: 1.0508x; 1.0508x over previous
//
#include <hip/hip_runtime.h>
#include <hip/hip_bf16.h>
#include <stdint.h>

// ViewLoRALinear: out[25088,1024] = x@W^T + b + (x@A_v)@B_v, fp32 in/out.
// Prep kernel casts x,W to bf16 (RNE) into d_ws and computes h = x@A_v in a
// single fused pass over x.
// GEMM (round 5): round-3's PROVEN 2-barrier schedule (stage -> sync ->
// ds_read+MFMA -> sync, BK=64, single buffer; latency hidden by block TLP,
// which round 3 proved is the lever: 4-deep residency gave 95->79.5us) with
// a 256x128 tile / 8 waves / 512 threads. Per-wave work unchanged (64x64
// out, 512 MFMA) but staging per thread per K-step drops 8 -> 6 gloads
// (-25%; global->LDS traffic 803 -> 602 MB) and residency is preserved:
// LDS 48 KB + ~124 regs/wave -> 2 blocks x 8 waves = 16 waves/CU (same as
// round 3). Round-4's BK=32 dbuf is reverted (79.5 -> 94.5 regression: 16
// MFMA per drain window cannot cover ~500cy load latency; it only doubled
// the number of exposed drains).
#define M_TOT 25088
#define N_TOT 1024
#define K_TOT 1024
#define NVIEW 11
#define ROWS_PER_VIEW 1568   // 8 frames * 196 tokens per view_idx entry

#define BM 256
#define BN 128
#define BK 64

#define GRID_G ((M_TOT / BM) * (N_TOT / BN))   // 98*8 = 784, %8 == 0

typedef unsigned short u16;
typedef __bf16 bf16x8 __attribute__((ext_vector_type(8)));
typedef float f32x4 __attribute__((ext_vector_type(4)));
typedef unsigned short u16x4 __attribute__((ext_vector_type(4)));

#define AS1 __attribute__((address_space(1)))
#define AS3 __attribute__((address_space(3)))

// ws layout (fast path): [x_bf16: 25088*1024 u16][W_bf16: 1024*1024 u16][h: 25088*4 f32]
#define XB_ELEMS ((size_t)M_TOT * K_TOT)
#define WB_ELEMS ((size_t)N_TOT * K_TOT)
#define WB_OFF_B (XB_ELEMS * 2)
#define H_OFF_B  (WB_OFF_B + WB_ELEMS * 2)
#define WS_NEEDED (H_OFF_B + (size_t)M_TOT * 4 * 4)

__device__ __forceinline__ u16 f2bf(float f) {
    union { float f; unsigned int i; } c; c.f = f;
    unsigned int i = c.i;
    return (u16)((i + 0x7FFFu + ((i >> 16) & 1u)) >> 16);  // RNE (finite inputs)
}

// ---------------------------------------------------------------------------
// Kernel 1: prep. Blocks 0..6271: one x-row per wave -> bf16 cast + h[row]
// in a SINGLE fused pass. Blocks 6272..6527: one W-row per wave -> bf16 cast.
// ---------------------------------------------------------------------------
__global__ __launch_bounds__(256) void prep_kernel(
    const float* __restrict__ x, const float* __restrict__ W,
    const int* __restrict__ view_idx, const float* __restrict__ lora_A,
    u16* __restrict__ xb, u16* __restrict__ wb, float* __restrict__ h) {
    const int wave = threadIdx.x >> 6;
    const int lane = threadIdx.x & 63;
    const int blk  = blockIdx.x;

    if (blk >= M_TOT / 4) {  // W cast
        const int row = (blk - M_TOT / 4) * 4 + wave;
        const float* src = W + (size_t)row * K_TOT;
        u16* dst = wb + (size_t)row * K_TOT;
#pragma unroll
        for (int it = 0; it < 4; ++it) {
            const int k = it * 256 + lane * 4;
            float4 v = *(const float4*)(src + k);
            u16x4 o = { f2bf(v.x), f2bf(v.y), f2bf(v.z), f2bf(v.w) };
            *(u16x4*)(dst + k) = o;
        }
        return;
    }

    const int row = blk * 4 + wave;
    int v = view_idx[row / ROWS_PER_VIEW];
    v = v < 0 ? 0 : (v > NVIEW - 1 ? NVIEW - 1 : v);
    const float* A  = lora_A + (size_t)v * (K_TOT * 4);  // [K][4] row-major
    const float* xr = x + (size_t)row * K_TOT;
    u16* dst = xb + (size_t)row * K_TOT;

    float a0 = 0.f, a1 = 0.f, a2 = 0.f, a3 = 0.f;
#pragma unroll
    for (int it = 0; it < 4; ++it) {
        const int k = it * 256 + lane * 4;
        float4 xv = *(const float4*)(xr + k);
        u16x4 o = { f2bf(xv.x), f2bf(xv.y), f2bf(xv.z), f2bf(xv.w) };
        *(u16x4*)(dst + k) = o;
        float4 av0 = *(const float4*)(A + (size_t)(k + 0) * 4);
        float4 av1 = *(const float4*)(A + (size_t)(k + 1) * 4);
        float4 av2 = *(const float4*)(A + (size_t)(k + 2) * 4);
        float4 av3 = *(const float4*)(A + (size_t)(k + 3) * 4);
        a0 += xv.x * av0.x + xv.y * av1.x + xv.z * av2.x + xv.w * av3.x;
        a1 += xv.x * av0.y + xv.y * av1.y + xv.z * av2.y + xv.w * av3.y;
        a2 += xv.x * av0.z + xv.y * av1.z + xv.z * av2.z + xv.w * av3.z;
        a3 += xv.x * av0.w + xv.y * av1.w + xv.z * av2.w + xv.w * av3.w;
    }
#pragma unroll
    for (int off = 32; off > 0; off >>= 1) {
        a0 += __shfl_xor(a0, off, 64);
        a1 += __shfl_xor(a1, off, 64);
        a2 += __shfl_xor(a2, off, 64);
        a3 += __shfl_xor(a3, off, 64);
    }
    if (lane == 0)
        *(float4*)(h + (size_t)row * 4) = make_float4(a0, a1, a2, a3);
}

// Fallback h (ws too small): fp32 x, one wave/row.
__global__ __launch_bounds__(256) void h_only_kernel(
    const float* __restrict__ x, const int* __restrict__ view_idx,
    const float* __restrict__ lora_A, float* __restrict__ h) {
    const int row  = blockIdx.x * 4 + (threadIdx.x >> 6);
    const int lane = threadIdx.x & 63;
    int v = view_idx[row / ROWS_PER_VIEW];
    v = v < 0 ? 0 : (v > NVIEW - 1 ? NVIEW - 1 : v);
    const float* A  = lora_A + (size_t)v * (K_TOT * 4);
    const float* xr = x + (size_t)row * K_TOT;
    float a0 = 0.f, a1 = 0.f, a2 = 0.f, a3 = 0.f;
#pragma unroll
    for (int it = 0; it < 4; ++it) {
        const int k = it * 256 + lane * 4;
        float4 xv = *(const float4*)(xr + k);
        float4 av0 = *(const float4*)(A + (size_t)(k + 0) * 4);
        float4 av1 = *(const float4*)(A + (size_t)(k + 1) * 4);
        float4 av2 = *(const float4*)(A + (size_t)(k + 2) * 4);
        float4 av3 = *(const float4*)(A + (size_t)(k + 3) * 4);
        a0 += xv.x * av0.x + xv.y * av1.x + xv.z * av2.x + xv.w * av3.x;
        a1 += xv.x * av0.y + xv.y * av1.y + xv.z * av2.y + xv.w * av3.y;
        a2 += xv.x * av0.z + xv.y * av1.z + xv.z * av2.z + xv.w * av3.z;
        a3 += xv.x * av0.w + xv.y * av1.w + xv.z * av2.w + xv.w * av3.w;
    }
#pragma unroll
    for (int off = 32; off > 0; off >>= 1) {
        a0 += __shfl_xor(a0, off, 64);
        a1 += __shfl_xor(a1, off, 64);
        a2 += __shfl_xor(a2, off, 64);
        a3 += __shfl_xor(a3, off, 64);
    }
    if (lane == 0)
        *(float4*)(h + (size_t)row * 4) = make_float4(a0, a1, a2, a3);
}

// ---------------------------------------------------------------------------
// Kernel 2 (fast path): GEMM C = X*W^T + bias + h*B_v, fp32 out.
// 256x128 tile, 8 waves (4M x 2N, 64x64 each), BK=64, round-3 schedule.
// LDS XOR-swizzle identical to round 3: slot (row r, chunk c) holds global
// chunk c^(r&7); fragment ds_read applies the same XOR -> 0 conflicts.
// ---------------------------------------------------------------------------
__device__ __forceinline__ void stage_tiles(const u16* __restrict__ gA,
                                            const u16* __restrict__ gB,
                                            u16* As, u16* Bs, int kofs, int tid) {
    // A: 256 rows x 64 cols = 32 KB -> 4 sweeps; B: 128 rows -> 2 sweeps.
    // 512 thr x 16 B per sweep. LDS dst linear; swizzle on SOURCE chunk.
#pragma unroll
    for (int i = 0; i < 4; ++i) {
        const int e = i * 4096 + tid * 8;
        const int r = e >> 6;
        const int c = (((tid & 7) ^ (r & 7)) << 3);
        __builtin_amdgcn_global_load_lds(
            (const AS1 void*)(gA + (size_t)r * K_TOT + kofs + c),
            (AS3 void*)(As + e), 16, 0, 0);
    }
#pragma unroll
    for (int i = 0; i < 2; ++i) {
        const int e = i * 4096 + tid * 8;
        const int r = e >> 6;
        const int c = (((tid & 7) ^ (r & 7)) << 3);
        __builtin_amdgcn_global_load_lds(
            (const AS1 void*)(gB + (size_t)r * K_TOT + kofs + c),
            (AS3 void*)(Bs + e), 16, 0, 0);
    }
}

__global__ __launch_bounds__(512, 4) void gemm_bf16_kernel(
    const u16* __restrict__ xb, const u16* __restrict__ wb,
    const float* __restrict__ bias, const int* __restrict__ view_idx,
    const float* __restrict__ lora_B, const float* __restrict__ h,
    float* __restrict__ out) {
    __shared__ u16 As[BM * BK];   // 32 KB
    __shared__ u16 Bs[BN * BK];   // 16 KB

    const int tid = threadIdx.x;
    // Bijective XCD swizzle (784 % 8 == 0): xcd = id&7 owns 98 consecutive
    // wgids; bx = wgid&7 -> one x-panel's 8 blocks are consecutive on an XCD.
    const int id   = blockIdx.x;
    const int wgid = (id & 7) * (GRID_G / 8) + (id >> 3);
    const int by   = wgid >> 3;          // 0..97
    const int bx   = wgid & 7;           // 0..7

    const int lane = tid & 63;
    const int wave = tid >> 6;
    const int wm   = (wave >> 1) * 64;   // 0,64,128,192
    const int wn   = (wave & 1) * 64;    // 0,64
    const int l16  = lane & 15;
    const int quad = lane >> 4;
    const int sw   = l16 & 7;            // fragment-read XOR key

    const u16* gA = xb + (size_t)(by * BM) * K_TOT;
    const u16* gB = wb + (size_t)(bx * BN) * K_TOT;

    f32x4 acc[4][4] = {};

    for (int kt = 0; kt < K_TOT / BK; ++kt) {
        stage_tiles(gA, gB, As, Bs, kt * BK, tid);
        __syncthreads();
#pragma unroll
        for (int kk = 0; kk < 2; ++kk) {
            const int csw = (((kk * 4 + quad) ^ sw) << 3);  // swizzled chunk offset
            bf16x8 a_frag[4], b_frag[4];
#pragma unroll
            for (int mi = 0; mi < 4; ++mi)
                a_frag[mi] = *(const bf16x8*)(const void*)(As + (wm + mi * 16 + l16) * BK + csw);
#pragma unroll
            for (int ni = 0; ni < 4; ++ni)
                b_frag[ni] = *(const bf16x8*)(const void*)(Bs + (wn + ni * 16 + l16) * BK + csw);
#pragma unroll
            for (int mi = 0; mi < 4; ++mi)
#pragma unroll
                for (int ni = 0; ni < 4; ++ni)
                    acc[mi][ni] = __builtin_amdgcn_mfma_f32_16x16x32_bf16(
                        a_frag[mi], b_frag[ni], acc[mi][ni], 0, 0, 0);
        }
        __syncthreads();
    }

    // Epilogue. C/D layout (m89): col = lane&15, row = quad*4 + reg.
    const int rowBase = by * BM + wm;
    const int colBase = bx * BN + wn;
    float biasv[4];
#pragma unroll
    for (int ni = 0; ni < 4; ++ni) biasv[ni] = bias[colBase + ni * 16 + l16];

    const int ve0 = (by * BM) / ROWS_PER_VIEW;
    const int ve1 = (by * BM + BM - 1) / ROWS_PER_VIEW;
    if (ve0 == ve1) {
        int v = view_idx[ve0];
        v = v < 0 ? 0 : (v > NVIEW - 1 ? NVIEW - 1 : v);
        const float* Bv = lora_B + (size_t)v * (4 * N_TOT);
        float Bvv[4][4];
#pragma unroll
        for (int r = 0; r < 4; ++r)
#pragma unroll
            for (int ni = 0; ni < 4; ++ni)
                Bvv[r][ni] = Bv[r * N_TOT + colBase + ni * 16 + l16];
#pragma unroll
        for (int mi = 0; mi < 4; ++mi) {
#pragma unroll
            for (int reg = 0; reg < 4; ++reg) {
                const int grow = rowBase + mi * 16 + quad * 4 + reg;
                const float4 hv = *(const float4*)(h + (size_t)grow * 4);
                float* orow = out + (size_t)grow * N_TOT;
#pragma unroll
                for (int ni = 0; ni < 4; ++ni) {
                    float lora = hv.x * Bvv[0][ni] + hv.y * Bvv[1][ni]
                               + hv.z * Bvv[2][ni] + hv.w * Bvv[3][ni];
                    orow[colBase + ni * 16 + l16] = acc[mi][ni][reg] + biasv[ni] + lora;
                }
            }
        }
    } else {
#pragma unroll
        for (int mi = 0; mi < 4; ++mi) {
#pragma unroll
            for (int reg = 0; reg < 4; ++reg) {
                const int grow = rowBase + mi * 16 + quad * 4 + reg;
                int v = view_idx[grow / ROWS_PER_VIEW];
                v = v < 0 ? 0 : (v > NVIEW - 1 ? NVIEW - 1 : v);
                const float4 hv = *(const float4*)(h + (size_t)grow * 4);
                const float* Bv = lora_B + (size_t)v * (4 * N_TOT);
                float* orow = out + (size_t)grow * N_TOT;
#pragma unroll
                for (int ni = 0; ni < 4; ++ni) {
                    const int gcol = colBase + ni * 16 + l16;
                    float lora = hv.x * Bv[gcol]
                               + hv.y * Bv[N_TOT + gcol]
                               + hv.z * Bv[2 * N_TOT + gcol]
                               + hv.w * Bv[3 * N_TOT + gcol];
                    orow[gcol] = acc[mi][ni][reg] + biasv[ni] + lora;
                }
            }
        }
    }
}

// ---------------------------------------------------------------------------
// Fallback GEMM (ws too small): 128x128, BK=64, in-kernel bf16 cast.
// ---------------------------------------------------------------------------
__global__ __launch_bounds__(256, 3) void gemm_conv_kernel(
    const float* __restrict__ xp, const float* __restrict__ Wp,
    const float* __restrict__ bias, const int* __restrict__ view_idx,
    const float* __restrict__ lora_B, const float* __restrict__ h,
    float* __restrict__ out) {
    __shared__ u16 As[128 * 64];
    __shared__ u16 Bs[128 * 64];

    const int tid = threadIdx.x;
    const int id = blockIdx.x;
    int bx, by;
    if (id < 1536) { const int c = id >> 6, w = id & 63; by = c * 8 + (w & 7); bx = w >> 3; }
    else           { const int r = id - 1536; by = 192 + (r & 3); bx = r >> 2; }

    const int lane = tid & 63;
    const int wave = tid >> 6;
    const int wm   = (wave >> 1) * 64;
    const int wn   = (wave & 1) * 64;
    const int l16  = lane & 15;
    const int quad = lane >> 4;
    const int sw   = l16 & 7;

    const size_t a_base = (size_t)(by * 128) * K_TOT;
    const size_t b_base = (size_t)(bx * 128) * K_TOT;

    f32x4 acc[4][4] = {};

    for (int kt = 0; kt < K_TOT / 64; ++kt) {
        const int kofs = kt * 64;
#pragma unroll
        for (int i = 0; i < 8; ++i) {
            const int e = i * 1024 + tid * 4;
            const int r = e >> 6, o = e & 63;
            const int d = r * 64 + (((o >> 3) ^ (r & 7)) << 3) + (o & 7);
            float4 av = *(const float4*)(xp + a_base + (size_t)r * K_TOT + kofs + o);
            float4 bv = *(const float4*)(Wp + b_base + (size_t)r * K_TOT + kofs + o);
            u16x4 ao = { f2bf(av.x), f2bf(av.y), f2bf(av.z), f2bf(av.w) };
            u16x4 bo = { f2bf(bv.x), f2bf(bv.y), f2bf(bv.z), f2bf(bv.w) };
            *(u16x4*)(As + d) = ao;
            *(u16x4*)(Bs + d) = bo;
        }
        __syncthreads();
#pragma unroll
        for (int kk = 0; kk < 2; ++kk) {
            const int csw = (((kk * 4 + quad) ^ sw) << 3);
            bf16x8 a_frag[4], b_frag[4];
#pragma unroll
            for (int mi = 0; mi < 4; ++mi)
                a_frag[mi] = *(const bf16x8*)(const void*)(As + (wm + mi * 16 + l16) * 64 + csw);
#pragma unroll
            for (int ni = 0; ni < 4; ++ni)
                b_frag[ni] = *(const bf16x8*)(const void*)(Bs + (wn + ni * 16 + l16) * 64 + csw);
#pragma unroll
            for (int mi = 0; mi < 4; ++mi)
#pragma unroll
                for (int ni = 0; ni < 4; ++ni)
                    acc[mi][ni] = __builtin_amdgcn_mfma_f32_16x16x32_bf16(
                        a_frag[mi], b_frag[ni], acc[mi][ni], 0, 0, 0);
        }
        __syncthreads();
    }

    const int rowBase = by * 128 + wm;
    const int colBase = bx * 128 + wn;
    float biasv[4];
#pragma unroll
    for (int ni = 0; ni < 4; ++ni) biasv[ni] = bias[colBase + ni * 16 + l16];
#pragma unroll
    for (int mi = 0; mi < 4; ++mi) {
#pragma unroll
        for (int reg = 0; reg < 4; ++reg) {
            const int grow = rowBase + mi * 16 + quad * 4 + reg;
            int v = view_idx[grow / ROWS_PER_VIEW];
            v = v < 0 ? 0 : (v > NVIEW - 1 ? NVIEW - 1 : v);
            const float4 hv = *(const float4*)(h + (size_t)grow * 4);
            const float* Bv = lora_B + (size_t)v * (4 * N_TOT);
            float* orow = out + (size_t)grow * N_TOT;
#pragma unroll
            for (int ni = 0; ni < 4; ++ni) {
                const int gcol = colBase + ni * 16 + l16;
                float lora = hv.x * Bv[gcol]
                           + hv.y * Bv[N_TOT + gcol]
                           + hv.z * Bv[2 * N_TOT + gcol]
                           + hv.w * Bv[3 * N_TOT + gcol];
                orow[gcol] = acc[mi][ni][reg] + biasv[ni] + lora;
            }
        }
    }
}

extern "C" void kernel_launch(void* const* d_in, const int* in_sizes, int n_in,
                              void* d_out, int out_size, void* d_ws, size_t ws_size,
                              hipStream_t stream) {
    const float* x        = (const float*)d_in[0];
    const int*   view_idx = (const int*)d_in[1];
    const float* W        = (const float*)d_in[2];
    const float* b        = (const float*)d_in[3];
    const float* lora_A   = (const float*)d_in[4];
    const float* lora_B   = (const float*)d_in[5];
    float* out = (float*)d_out;

    if (ws_size >= WS_NEEDED) {
        u16*   xb = (u16*)d_ws;
        u16*   wb = (u16*)((char*)d_ws + WB_OFF_B);
        float* h  = (float*)((char*)d_ws + H_OFF_B);
        hipLaunchKernelGGL(prep_kernel, dim3(M_TOT / 4 + N_TOT / 4), dim3(256), 0, stream,
                           x, W, view_idx, lora_A, xb, wb, h);
        hipLaunchKernelGGL(gemm_bf16_kernel, dim3(GRID_G), dim3(512), 0, stream,
                           xb, wb, b, view_idx, lora_B, h, out);
    } else {
        float* h = (float*)d_ws;  // 401,408 B
        hipLaunchKernelGGL(h_only_kernel, dim3(M_TOT / 4), dim3(256), 0, stream,
                           x, view_idx, lora_A, h);
        hipLaunchKernelGGL(gemm_conv_kernel, dim3((M_TOT / 128) * (N_TOT / 128)), dim3(256), 0, stream,
                           x, W, b, view_idx, lora_B, h, out);
    }
}